// Round 6
// baseline (117.633 us; speedup 1.0000x reference)
//
#include <hip/hip_runtime.h>
#include <math.h>

#define DEV static __device__ __forceinline__

constexpr int SS = 12;
constexpr int NN = 207;
constexpr int NCIRC = 64 * NN;          // 13248 circuits
constexpr int NPAIR = NCIRC / 2;        // 6624 waves, 2 circuits each
// pair (g, g+6624): 6624 = 32*207 -> same node, b differs by 32 -> shared
// adjacency mask + branches; conv matrices shared; only state/x duplicate.

// Lane layout per circuit: amplitude index i = (lane<<2) | k, k=0..3.
// Amp bits 0,1 = in-lane K slots (v2f a0..a3 = (re,im)); amp bit b>=2 =
// lane bit b-2. Qubit q starts at amp bit (7-q). Conv pair = one real 4x4
// matrix (prep_kernel) applied to the K slots.
// Hard rules: no runtime-indexed state arrays (R2/R3: SROA fail -> LDS
// demotion, 4.45M conflicts); static-mask __shfl_xor for all fixed moves.

typedef float v2f __attribute__((ext_vector_type(2)));

DEV v2f splat2(float x) { v2f r; r.x = x; r.y = x; return r; }
DEV v2f vfma(float m, v2f a, v2f acc) { return __builtin_elementwise_fma(splat2(m), a, acc); }
DEV v2f vmul(float m, v2f a) { return splat2(m) * a; }
template<int M> DEV float sxc(float v) { return __shfl_xor(v, M, 64); }
template<int M> DEV v2f sx2(v2f v) { v2f r; r.x = sxc<M>(v.x); r.y = sxc<M>(v.y); return r; }

struct Ct { v2f a0, a1, a2, a3; };

DEV void convm(Ct& s, const float* __restrict__ P) {
    v2f b0 = s.a0, b1 = s.a1, b2 = s.a2, b3 = s.a3;
    s.a0 = vfma(P[0],  b0, vfma(P[1],  b1, vfma(P[2],  b2, vmul(P[3],  b3))));
    s.a1 = vfma(P[4],  b0, vfma(P[5],  b1, vfma(P[6],  b2, vmul(P[7],  b3))));
    s.a2 = vfma(P[8],  b0, vfma(P[9],  b1, vfma(P[10], b2, vmul(P[11], b3))));
    s.a3 = vfma(P[12], b0, vfma(P[13], b1, vfma(P[14], b2, vmul(P[15], b3))));
}

// swap in-lane amp bit 1 with lane bit J
template<int J> DEV void swkl1(Ct& s, int lane) {
    const bool lb = (lane >> J) & 1;
    v2f t0 = sx2<(1 << J)>(s.a2), t1 = sx2<(1 << J)>(s.a3);
    v2f t2 = sx2<(1 << J)>(s.a0), t3 = sx2<(1 << J)>(s.a1);
    s.a0 = lb ? t0 : s.a0; s.a1 = lb ? t1 : s.a1;
    s.a2 = lb ? s.a2 : t2; s.a3 = lb ? s.a3 : t3;
}

// swap in-lane amp bit 0 with lane bit J
template<int J> DEV void swkl0(Ct& s, int lane) {
    const bool lb = (lane >> J) & 1;
    v2f t0 = sx2<(1 << J)>(s.a1), t1 = sx2<(1 << J)>(s.a0);
    v2f t2 = sx2<(1 << J)>(s.a3), t3 = sx2<(1 << J)>(s.a2);
    s.a0 = lb ? t0 : s.a0; s.a1 = lb ? s.a1 : t1;
    s.a2 = lb ? t2 : s.a2; s.a3 = lb ? s.a3 : t3;
}

// RY on lane-resident qubit at lane bit J (pool gates)
template<int J> DEV void ryl(Ct& s, int lane, float c, float sv) {
    const float sg = ((lane >> J) & 1) ? sv : -sv;
    v2f p;
    p = sx2<(1 << J)>(s.a0); s.a0 = __builtin_elementwise_fma(splat2(c), s.a0, vmul(sg, p));
    p = sx2<(1 << J)>(s.a1); s.a1 = __builtin_elementwise_fma(splat2(c), s.a1, vmul(sg, p));
    p = sx2<(1 << J)>(s.a2); s.a2 = __builtin_elementwise_fma(splat2(c), s.a2, vmul(sg, p));
    p = sx2<(1 << J)>(s.a3); s.a3 = __builtin_elementwise_fma(splat2(c), s.a3, vmul(sg, p));
}

// angles -> analytic product state (RY layer + RZ phases)
DEV Ct init_state(const float* __restrict__ xp, const float* __restrict__ w_proj,
                  const float* __restrict__ b_proj, int lane) {
    v2f av[8];
#pragma unroll
    for (int k = 0; k < 8; k++) av[k] = splat2(0.0f);
#pragma unroll
    for (int s = 0; s < SS; s++) {
        const v2f xv = *(const v2f*)(xp + (size_t)s * (NN * 2));
#pragma unroll
        for (int k = 0; k < 8; k++) {
            const v2f wv2 = *(const v2f*)(w_proj + k * 24 + 2 * s);
            av[k] = __builtin_elementwise_fma(xv, wv2, av[k]);
        }
    }
    const float PI_F = 3.14159265358979323846f;
    float ang[8];
#pragma unroll
    for (int k = 0; k < 8; k++)
        ang[k] = fminf(fmaxf(av[k].x + av[k].y + b_proj[k], -PI_F), PI_F);
    float cc[8], ssn[8];
#pragma unroll
    for (int i = 0; i < 8; i++) __sincosf(0.5f * ang[i], &ssn[i], &cc[i]);
    float A = 1.0f;
#pragma unroll
    for (int i = 0; i < 6; i++)              // qubits 0..5 -> lane bits 5-i
        A *= ((lane >> (5 - i)) & 1) ? ssn[i] : cc[i];
    float phi = 0.0f;
#pragma unroll
    for (int i = 0; i < 4; i++)              // RZ on qubits 0..3 (lane bits 5..2)
        phi += ((lane >> (5 - i)) & 1) ? 0.5f * ang[4 + i] : -0.5f * ang[4 + i];
    float cp, sp;
    __sincosf(phi, &sp, &cp);
    v2f ph; ph.x = cp; ph.y = sp;
    Ct s;
    s.a0 = vmul(A * cc[6] * cc[7], ph);
    s.a1 = vmul(A * cc[6] * ssn[7], ph);
    s.a2 = vmul(A * ssn[6] * cc[7], ph);
    s.a3 = vmul(A * ssn[6] * ssn[7], ph);
    return s;
}

// adjacency permutation gather (uniform Mlane/Mlo)
DEV Ct adj_gather(const Ct& s, int Mlane, int Mlo) {
    v2f p0, p1, p2, p3;
    if (Mlo == 0)      { p0 = s.a0; p1 = s.a1; p2 = s.a2; p3 = s.a3; }
    else if (Mlo == 1) { p0 = s.a1; p1 = s.a0; p2 = s.a3; p3 = s.a2; }
    else if (Mlo == 2) { p0 = s.a2; p1 = s.a3; p2 = s.a0; p3 = s.a1; }
    else               { p0 = s.a3; p1 = s.a2; p2 = s.a1; p3 = s.a0; }
    p0.x = __shfl_xor(p0.x, Mlane, 64); p0.y = __shfl_xor(p0.y, Mlane, 64);
    p1.x = __shfl_xor(p1.x, Mlane, 64); p1.y = __shfl_xor(p1.y, Mlane, 64);
    p2.x = __shfl_xor(p2.x, Mlane, 64); p2.y = __shfl_xor(p2.y, Mlane, 64);
    p3.x = __shfl_xor(p3.x, Mlane, 64); p3.y = __shfl_xor(p3.y, Mlane, 64);
    Ct r; r.a0 = p0; r.a1 = p1; r.a2 = p2; r.a3 = p3;
    return r;
}

DEV void adj_select(Ct& s, const Ct& p, int pc, int lane) {
    if (pc >= 2) {
        const bool bb = (lane >> (pc - 2)) & 1;
        s.a0 = bb ? p.a0 : s.a0; s.a1 = bb ? p.a1 : s.a1;
        s.a2 = bb ? p.a2 : s.a2; s.a3 = bb ? p.a3 : s.a3;
    } else if (pc == 1) { s.a2 = p.a2; s.a3 = p.a3; }
    else                { s.a1 = p.a1; s.a3 = p.a3; }
}

// z-vector build + 6-stage butterfly broadcast
DEV void build_z(const Ct& s, int lane, v2f& za, v2f& zb, v2f& zc, v2f& zd) {
    const float p0 = fmaf(s.a0.x, s.a0.x, s.a0.y * s.a0.y);
    const float p1 = fmaf(s.a1.x, s.a1.x, s.a1.y * s.a1.y);
    const float p2 = fmaf(s.a2.x, s.a2.x, s.a2.y * s.a2.y);
    const float p3 = fmaf(s.a3.x, s.a3.x, s.a3.y * s.a3.y);
    const float psum = (p0 + p1) + (p2 + p3);
    // final layout: K1=q6, K0=q5 | L5=q2, L4=q7, L3=q4, L2=q1, L1=q0, L0=q3
    za.x = ((lane >> 1) & 1) ? -psum : psum;    // q0 = L1
    za.y = ((lane >> 2) & 1) ? -psum : psum;    // q1 = L2
    zb.x = ((lane >> 5) & 1) ? -psum : psum;    // q2 = L5
    zb.y = (lane & 1)        ? -psum : psum;    // q3 = L0
    zc.x = ((lane >> 3) & 1) ? -psum : psum;    // q4 = L3
    zc.y = (p0 - p1) + (p2 - p3);               // q5 = K0
    zd.x = (p0 + p1) - (p2 + p3);               // q6 = K1
    zd.y = ((lane >> 4) & 1) ? -psum : psum;    // q7 = L4
#define BFLY(MM) do { za += sx2<MM>(za); zb += sx2<MM>(zb);               \
                      zc += sx2<MM>(zc); zd += sx2<MM>(zd); } while (0)
    BFLY(1); BFLY(2); BFLY(4); BFLY(8); BFLY(16); BFLY(32);
#undef BFLY
}

// ---- prep kernel: fuse each conv pair into one real 4x4 matrix (R5-verified) --
__global__ void prep_kernel(const float* __restrict__ qp, float* __restrict__ ws) {
    const int n = threadIdx.x;
    if (n == 14) {
        float s, c;
        sincosf(0.5f * qp[56], &s, &c); ws[224] = c; ws[225] = s;
        sincosf(0.5f * qp[58], &s, &c); ws[226] = c; ws[227] = s;
        sincosf(0.5f * qp[60], &s, &c); ws[228] = c; ws[229] = s;
    }
    if (n >= 14) return;
    const int Jt[14] = {12, 8, 24, 4, 20, 0, 16, 32, 28, 44, 36, 48, 40, 52};
    const int Vt[14] = { 0, 0,  1, 0,  1, 0,  1,  0,  0,  1,  0,  1,  0,  1};
    const int J = Jt[n], v = Vt[n];
    float cg[4], sg[4];
    for (int i = 0; i < 4; i++) sincosf(0.5f * qp[J + i], &sg[i], &cg[i]);
    const int h1i = v ? 1 : 0, l1i = v ? 0 : 1;
    const int h2i = v ? 3 : 2, l2i = v ? 2 : 3;
    float A[16], B[16], M[16];
    {
        float H[2][2] = {{cg[h1i], -sg[h1i]}, {sg[h1i], cg[h1i]}};
        float L[2][2] = {{cg[l1i], -sg[l1i]}, {sg[l1i], cg[l1i]}};
        for (int a = 0; a < 2; a++) for (int b = 0; b < 2; b++)
            for (int p = 0; p < 2; p++) for (int q = 0; q < 2; q++)
                A[(2*a+b)*4 + (2*p+q)] = H[a][p] * L[b][q];
    }
    { const int ra = v ? 1 : 2;
      for (int j = 0; j < 4; j++) { float t = A[ra*4+j]; A[ra*4+j] = A[12+j]; A[12+j] = t; } }
    {
        float H[2][2] = {{cg[h2i], -sg[h2i]}, {sg[h2i], cg[h2i]}};
        float L[2][2] = {{cg[l2i], -sg[l2i]}, {sg[l2i], cg[l2i]}};
        for (int a = 0; a < 2; a++) for (int b = 0; b < 2; b++)
            for (int p = 0; p < 2; p++) for (int q = 0; q < 2; q++)
                B[(2*a+b)*4 + (2*p+q)] = H[a][p] * L[b][q];
    }
    for (int r = 0; r < 4; r++)
        for (int cl = 0; cl < 4; cl++) {
            float acc = 0.0f;
            for (int k = 0; k < 4; k++) acc += B[r*4+k] * A[k*4+cl];
            M[r*4+cl] = acc;
        }
    { const int rb = v ? 2 : 1;
      for (int j = 0; j < 4; j++) { float t = M[rb*4+j]; M[rb*4+j] = M[12+j]; M[12+j] = t; } }
    if (n == 13) {
        float ps, pc;
        sincosf(0.5f * qp[62], &ps, &pc);
        for (int j = 0; j < 4; j++) {
            float r0 = M[j],   r2 = M[8+j];
            M[j]   = pc * r0 - ps * r2;  M[8+j]  = ps * r0 + pc * r2;
            float r1 = M[4+j], r3 = M[12+j];
            M[4+j] = pc * r1 - ps * r3;  M[12+j] = ps * r1 + pc * r3;
        }
    }
    for (int i = 0; i < 16; i++) ws[16*n + i] = M[i];
}

__global__ __launch_bounds__(256) void qcnn_kernel(
    const float* __restrict__ x, const float* __restrict__ adj,
    const float* __restrict__ w_proj, const float* __restrict__ b_proj,
    const float* __restrict__ ws,
    const float* __restrict__ w1, const float* __restrict__ b1,
    const float* __restrict__ w2, const float* __restrict__ b2,
    const float* __restrict__ w3, const float* __restrict__ b3,
    float* __restrict__ out)
{
    const int lane = threadIdx.x & 63;
    const int wv   = threadIdx.x >> 6;
    const int gA   = blockIdx.x * 4 + wv;        // grid exact: 1656*4 == 6624
    const int gB   = gA + NPAIR;                 // same node, b += 32
    const int bA   = gA / NN;
    const int node = gA - bA * NN;

    const float* xpA = x + ((size_t)bA * SS * NN + node) * 2;
    const float* xpB = xpA + (size_t)32 * SS * NN * 2;

    Ct sA = init_state(xpA, w_proj, b_proj, lane);
    Ct sB = init_state(xpB, w_proj, b_proj, lane);

    // ---- adjacency permutation: shared mask (same node for both circuits) --
    const int cq = node & 7;
    int M = 0;
#pragma unroll
    for (int t = 0; t < 8; t++) {
        float avv = adj[cq * NN + t];
        if (t != cq && avv > 0.0f) M |= 1 << (7 - t);
    }
    if (M) {
        const int Mlane = M >> 2, Mlo = M & 3, pc = 7 - cq;
        Ct pA = adj_gather(sA, Mlane, Mlo);
        Ct pB = adj_gather(sB, Mlane, Mlo);
        adj_select(sA, pA, pc, lane);
        adj_select(sB, pB, pc, lane);
    }

    // ---- conv layers: fused 4x4 matrices + relayout (schedule R4-verified) --
    // Slot map: K1,K0 | L5..L0; init: 6,7 | 0,1,2,3,4,5
#define C2(OFF)  do { convm(sA, ws + (OFF)); convm(sB, ws + (OFF)); } while (0)
#define S12(J)   do { swkl1<J>(sA, lane); swkl1<J>(sB, lane); } while (0)
#define S02(J)   do { swkl0<J>(sA, lane); swkl0<J>(sB, lane); } while (0)
    C2(0);                       // (6,7)
    S12(1); S02(0);              // 4,5 | 0,1,2,3,6,7
    C2(16);                      // (4,5)
    S12(1);                      // 6,5 | 0,1,2,3,4,7
    C2(32);                      // (5,6)
    S12(3); S02(2);              // 2,3 | 0,1,6,5,4,7
    C2(48);                      // (2,3)
    S12(1);                      // 4,3 | 0,1,6,5,2,7
    C2(64);                      // (3,4)
    S12(5); S02(4);              // 0,1 | 4,3,6,5,2,7
    C2(80);                      // (0,1)
    S12(1);                      // 2,1 | 4,3,6,5,0,7
    C2(96);                      // (1,2)
    // layer 2
    S02(4);                      // 2,3 | 4,1,6,5,0,7
    C2(112);                     // (2,3)
    S12(1); S02(4);              // 0,1 | 4,3,6,5,2,7
    C2(128);                     // (0,1)
    S12(1);                      // 2,1 | 4,3,6,5,0,7
    C2(144);                     // (1,2)
    S12(5); S02(2);              // 4,5 | 2,3,6,1,0,7
    C2(160);                     // (4,5)
    S02(4);                      // 4,3 | 2,5,6,1,0,7
    C2(176);                     // (3,4)
    S12(3); S02(0);              // 6,7 | 2,5,4,1,0,3
    C2(192);                     // (6,7)
    S02(4);                      // 6,5 | 2,7,4,1,0,3
    C2(208);                     // (5,6) + pool RY(q6) folded
#undef C2
#undef S12
#undef S02
    // final layout: K1=q6, K0=q5 | L5=q2, L4=q7, L3=q4, L2=q1, L1=q0, L0=q3

    // ---- pool: RY on q0(L1), q2(L5), q4(L3) ----
    ryl<1>(sA, lane, ws[224], ws[225]); ryl<1>(sB, lane, ws[224], ws[225]);
    ryl<5>(sA, lane, ws[226], ws[227]); ryl<5>(sB, lane, ws[226], ws[227]);
    ryl<3>(sA, lane, ws[228], ws[229]); ryl<3>(sB, lane, ws[228], ws[229]);

    // ---- z + broadcast ----
    v2f zaA, zbA, zcA, zdA, zaB, zbB, zcB, zdB;
    build_z(sA, lane, zaA, zbA, zcA, zdA);
    build_z(sB, lane, zaB, zbB, zcB, zdB);

    // ---- MLP head: 8 -> 64 (relu) -> 32 (relu) -> 1 ----
    const v2f* w1v = (const v2f*)(w1 + lane * 8);   // shared row for A and B
    const v2f w10 = w1v[0], w11 = w1v[1], w12 = w1v[2], w13 = w1v[3];
    v2f hA = zaA * w10;
    hA = __builtin_elementwise_fma(zbA, w11, hA);
    hA = __builtin_elementwise_fma(zcA, w12, hA);
    hA = __builtin_elementwise_fma(zdA, w13, hA);
    v2f hB = zaB * w10;
    hB = __builtin_elementwise_fma(zbB, w11, hB);
    hB = __builtin_elementwise_fma(zcB, w12, hB);
    hB = __builtin_elementwise_fma(zdB, w13, hB);
    const float bb1 = b1[lane];
    const float h1A = fmaxf(bb1 + hA.x + hA.y, 0.0f);
    const float h1B = fmaxf(bb1 + hB.x + hB.y, 0.0f);

    // wave-local LDS staging (no __syncthreads needed: same wave writes/reads)
    __shared__ float h1s[8][64];
    h1s[2 * wv][lane]     = h1A;
    h1s[2 * wv + 1][lane] = h1B;

    // half 0 computes circuit A's h2, half 1 circuit B's
    const int m = lane & 31;
    const v2f* hsv = (const v2f*)(&h1s[2 * wv + (lane >> 5)][0]);
    const v2f* w2v = (const v2f*)(w2 + m * 64);
    v2f acc2 = splat2(0.0f);
#pragma unroll
    for (int j = 0; j < 32; j++)
        acc2 = __builtin_elementwise_fma(hsv[j], w2v[j], acc2);
    const float h2 = fmaxf(b2[m] + acc2.x + acc2.y, 0.0f);

    float o = h2 * w3[m];
    o += sxc<1>(o); o += sxc<2>(o); o += sxc<4>(o); o += sxc<8>(o); o += sxc<16>(o);

    if (m == 0) out[(lane >> 5) ? gB : gA] = o + b3[0];
}

extern "C" void kernel_launch(void* const* d_in, const int* in_sizes, int n_in,
                              void* d_out, int out_size, void* d_ws, size_t ws_size,
                              hipStream_t stream) {
    const float* x      = (const float*)d_in[0];
    const float* adj    = (const float*)d_in[1];
    const float* w_proj = (const float*)d_in[2];
    const float* b_proj = (const float*)d_in[3];
    const float* qp     = (const float*)d_in[4];
    const float* w1     = (const float*)d_in[5];
    const float* b1     = (const float*)d_in[6];
    const float* w2     = (const float*)d_in[7];
    const float* b2     = (const float*)d_in[8];
    const float* w3     = (const float*)d_in[9];
    const float* b3     = (const float*)d_in[10];
    float* out = (float*)d_out;
    float* ws  = (float*)d_ws;                 // 230 floats

    hipLaunchKernelGGL(prep_kernel, dim3(1), dim3(64), 0, stream, qp, ws);
    hipLaunchKernelGGL(qcnn_kernel, dim3(NPAIR / 4), dim3(256), 0, stream,
                       x, adj, w_proj, b_proj, ws, w1, b1, w2, b2, w3, b3, out);
}

// Round 7
// 104.629 us; speedup vs baseline: 1.1243x; 1.1243x over previous
//
#include <hip/hip_runtime.h>
#include <math.h>

#define DEV static __device__ __forceinline__

constexpr int SS = 12;
constexpr int NN = 207;
constexpr int NCIRC = 64 * NN;          // 13248 circuits
constexpr int NPAIR = NCIRC / 2;        // 6624 waves, 2 circuits each
// pair (g, g+6624): 6624 = 32*207 -> same node -> shared adjacency mask,
// conv matrices, w1/w2 rows; only state/x duplicate.

// Lane layout per circuit: amplitude index i = (lane<<2) | k, k=0..3.
// Amp bits 0,1 = in-lane K slots (v2f a0..a3 = (re,im)); amp bit b>=2 =
// lane bit b-2. Qubit q starts at amp bit (7-q). Conv pair = one real 4x4
// matrix (prep_kernel) applied to the K slots.
// Hard rules: no runtime-indexed state arrays (R2/R3: SROA fail -> LDS
// demotion); static-mask __shfl_xor; ds-pipe op count is THE resource
// (R6: per-CU ds pipe bound at VALUBusy 32%), so swaps use the
// half-shuffle trick and z-reduction uses WHT + readlane.

typedef float v2f __attribute__((ext_vector_type(2)));
typedef float v4f __attribute__((ext_vector_type(4)));

DEV v2f splat2(float x) { v2f r; r.x = x; r.y = x; return r; }
DEV v2f vfma(float m, v2f a, v2f acc) { return __builtin_elementwise_fma(splat2(m), a, acc); }
DEV v2f vmul(float m, v2f a) { return splat2(m) * a; }
template<int M> DEV float sxc(float v) { return __shfl_xor(v, M, 64); }
template<int M> DEV v2f sx2(v2f v) { v2f r; r.x = sxc<M>(v.x); r.y = sxc<M>(v.y); return r; }
DEV float rdl(float v, int l) {
    return __int_as_float(__builtin_amdgcn_readlane(__float_as_int(v), l));
}

struct Ct { v2f a0, a1, a2, a3; };

DEV void convm(Ct& s, const float* __restrict__ P) {
    v2f b0 = s.a0, b1 = s.a1, b2 = s.a2, b3 = s.a3;
    s.a0 = vfma(P[0],  b0, vfma(P[1],  b1, vfma(P[2],  b2, vmul(P[3],  b3))));
    s.a1 = vfma(P[4],  b0, vfma(P[5],  b1, vfma(P[6],  b2, vmul(P[7],  b3))));
    s.a2 = vfma(P[8],  b0, vfma(P[9],  b1, vfma(P[10], b2, vmul(P[11], b3))));
    s.a3 = vfma(P[12], b0, vfma(P[13], b1, vfma(P[14], b2, vmul(P[15], b3))));
}

// Half-shuffle swap of in-lane amp bit 1 with lane bit J (2 v2f shuffles).
// lb=1 lanes send a0,a1 and receive partner a2,a3 into a0,a1; lb=0 converse.
template<int J> DEV void swkl1(Ct& s, int lane) {
    const bool lb = (lane >> J) & 1;
    v2f u0 = lb ? s.a0 : s.a2;
    v2f u1 = lb ? s.a1 : s.a3;
    v2f v0 = sx2<(1 << J)>(u0);
    v2f v1 = sx2<(1 << J)>(u1);
    s.a0 = lb ? v0 : s.a0;
    s.a1 = lb ? v1 : s.a1;
    s.a2 = lb ? s.a2 : v0;
    s.a3 = lb ? s.a3 : v1;
}

// Half-shuffle swap of in-lane amp bit 0 with lane bit J.
template<int J> DEV void swkl0(Ct& s, int lane) {
    const bool lb = (lane >> J) & 1;
    v2f u0 = lb ? s.a0 : s.a1;
    v2f u1 = lb ? s.a2 : s.a3;
    v2f v0 = sx2<(1 << J)>(u0);
    v2f v1 = sx2<(1 << J)>(u1);
    s.a0 = lb ? v0 : s.a0;
    s.a1 = lb ? s.a1 : v0;
    s.a2 = lb ? v1 : s.a2;
    s.a3 = lb ? s.a3 : v1;
}

// In-lane RY on K-bit 0: rotate (a0,a1) and (a2,a3).
DEV void ry_k0(Ct& s, float c, float sv) {
    v2f b0 = s.a0, b2 = s.a2;
    s.a0 = vfma(c, b0, vmul(-sv, s.a1));
    s.a1 = vfma(sv, b0, vmul(c, s.a1));
    s.a2 = vfma(c, b2, vmul(-sv, s.a3));
    s.a3 = vfma(sv, b2, vmul(c, s.a3));
}

// In-lane RY on K-bit 1: rotate (a0,a2) and (a1,a3).
DEV void ry_k1(Ct& s, float c, float sv) {
    v2f b0 = s.a0, b1 = s.a1;
    s.a0 = vfma(c, b0, vmul(-sv, s.a2));
    s.a2 = vfma(sv, b0, vmul(c, s.a2));
    s.a1 = vfma(c, b1, vmul(-sv, s.a3));
    s.a3 = vfma(sv, b1, vmul(c, s.a3));
}

// One WHT butterfly stage over lane-bit mask MK.
template<int MK> DEV float whts(float p, int lane) {
    float t = sxc<MK>(p);
    return (lane & MK) ? (t - p) : (p + t);
}

// angles -> analytic product state (RY layer + RZ phases)
DEV Ct init_state(const float* __restrict__ xp, const float* __restrict__ w_proj,
                  const float* __restrict__ b_proj, int lane) {
    v2f av[8];
#pragma unroll
    for (int k = 0; k < 8; k++) av[k] = splat2(0.0f);
#pragma unroll
    for (int s = 0; s < SS; s++) {
        const v2f xv = *(const v2f*)(xp + (size_t)s * (NN * 2));
#pragma unroll
        for (int k = 0; k < 8; k++) {
            const v2f wv2 = *(const v2f*)(w_proj + k * 24 + 2 * s);
            av[k] = __builtin_elementwise_fma(xv, wv2, av[k]);
        }
    }
    const float PI_F = 3.14159265358979323846f;
    float ang[8];
#pragma unroll
    for (int k = 0; k < 8; k++)
        ang[k] = fminf(fmaxf(av[k].x + av[k].y + b_proj[k], -PI_F), PI_F);
    float cc[8], ssn[8];
#pragma unroll
    for (int i = 0; i < 8; i++) __sincosf(0.5f * ang[i], &ssn[i], &cc[i]);
    float A = 1.0f;
#pragma unroll
    for (int i = 0; i < 6; i++)              // qubits 0..5 -> lane bits 5-i
        A *= ((lane >> (5 - i)) & 1) ? ssn[i] : cc[i];
    float phi = 0.0f;
#pragma unroll
    for (int i = 0; i < 4; i++)              // RZ on qubits 0..3 (lane bits 5..2)
        phi += ((lane >> (5 - i)) & 1) ? 0.5f * ang[4 + i] : -0.5f * ang[4 + i];
    float cp, sp;
    __sincosf(phi, &sp, &cp);
    v2f ph; ph.x = cp; ph.y = sp;
    Ct s;
    s.a0 = vmul(A * cc[6] * cc[7], ph);
    s.a1 = vmul(A * cc[6] * ssn[7], ph);
    s.a2 = vmul(A * ssn[6] * cc[7], ph);
    s.a3 = vmul(A * ssn[6] * ssn[7], ph);
    return s;
}

// adjacency permutation gather (uniform Mlane/Mlo)
DEV Ct adj_gather(const Ct& s, int Mlane, int Mlo) {
    v2f p0, p1, p2, p3;
    if (Mlo == 0)      { p0 = s.a0; p1 = s.a1; p2 = s.a2; p3 = s.a3; }
    else if (Mlo == 1) { p0 = s.a1; p1 = s.a0; p2 = s.a3; p3 = s.a2; }
    else if (Mlo == 2) { p0 = s.a2; p1 = s.a3; p2 = s.a0; p3 = s.a1; }
    else               { p0 = s.a3; p1 = s.a2; p2 = s.a1; p3 = s.a0; }
    p0.x = __shfl_xor(p0.x, Mlane, 64); p0.y = __shfl_xor(p0.y, Mlane, 64);
    p1.x = __shfl_xor(p1.x, Mlane, 64); p1.y = __shfl_xor(p1.y, Mlane, 64);
    p2.x = __shfl_xor(p2.x, Mlane, 64); p2.y = __shfl_xor(p2.y, Mlane, 64);
    p3.x = __shfl_xor(p3.x, Mlane, 64); p3.y = __shfl_xor(p3.y, Mlane, 64);
    Ct r; r.a0 = p0; r.a1 = p1; r.a2 = p2; r.a3 = p3;
    return r;
}

DEV void adj_select(Ct& s, const Ct& p, int pc, int lane) {
    if (pc >= 2) {
        const bool bb = (lane >> (pc - 2)) & 1;
        s.a0 = bb ? p.a0 : s.a0; s.a1 = bb ? p.a1 : s.a1;
        s.a2 = bb ? p.a2 : s.a2; s.a3 = bb ? p.a3 : s.a3;
    } else if (pc == 1) { s.a2 = p.a2; s.a3 = p.a3; }
    else                { s.a1 = p.a1; s.a3 = p.a3; }
}

// z reduction: WHT on psum (6 stages, 1 scalar) + packed plain butterfly for
// the two K-slot z's. Outputs: W = per-lane WHT coeffs, dk = uniform (zK0,zK1).
DEV void build_z(const Ct& s, int lane, float& W, v2f& dk) {
    const float p0 = fmaf(s.a0.x, s.a0.x, s.a0.y * s.a0.y);
    const float p1 = fmaf(s.a1.x, s.a1.x, s.a1.y * s.a1.y);
    const float p2 = fmaf(s.a2.x, s.a2.x, s.a2.y * s.a2.y);
    const float p3 = fmaf(s.a3.x, s.a3.x, s.a3.y * s.a3.y);
    dk.x = (p0 - p1) + (p2 - p3);            // K0 z-contrib
    dk.y = (p0 + p1) - (p2 + p3);            // K1 z-contrib
    float w = (p0 + p1) + (p2 + p3);         // psum
    w = whts<1>(w, lane);  w = whts<2>(w, lane);  w = whts<4>(w, lane);
    w = whts<8>(w, lane);  w = whts<16>(w, lane); w = whts<32>(w, lane);
    W = w;                                   // lane L holds WHT coeff W(L)
    dk += sx2<1>(dk);  dk += sx2<2>(dk);  dk += sx2<4>(dk);
    dk += sx2<8>(dk);  dk += sx2<16>(dk); dk += sx2<32>(dk);
}

// ---- prep kernel: fuse each conv pair into one real 4x4 matrix (R5-verified) --
__global__ void prep_kernel(const float* __restrict__ qp, float* __restrict__ ws) {
    const int n = threadIdx.x;
    if (n == 14) {
        float s, c;
        sincosf(0.5f * qp[56], &s, &c); ws[224] = c; ws[225] = s;
        sincosf(0.5f * qp[58], &s, &c); ws[226] = c; ws[227] = s;
        sincosf(0.5f * qp[60], &s, &c); ws[228] = c; ws[229] = s;
    }
    if (n >= 14) return;
    const int Jt[14] = {12, 8, 24, 4, 20, 0, 16, 32, 28, 44, 36, 48, 40, 52};
    const int Vt[14] = { 0, 0,  1, 0,  1, 0,  1,  0,  0,  1,  0,  1,  0,  1};
    const int J = Jt[n], v = Vt[n];
    float cg[4], sg[4];
    for (int i = 0; i < 4; i++) sincosf(0.5f * qp[J + i], &sg[i], &cg[i]);
    const int h1i = v ? 1 : 0, l1i = v ? 0 : 1;
    const int h2i = v ? 3 : 2, l2i = v ? 2 : 3;
    float A[16], B[16], M[16];
    {
        float H[2][2] = {{cg[h1i], -sg[h1i]}, {sg[h1i], cg[h1i]}};
        float L[2][2] = {{cg[l1i], -sg[l1i]}, {sg[l1i], cg[l1i]}};
        for (int a = 0; a < 2; a++) for (int b = 0; b < 2; b++)
            for (int p = 0; p < 2; p++) for (int q = 0; q < 2; q++)
                A[(2*a+b)*4 + (2*p+q)] = H[a][p] * L[b][q];
    }
    { const int ra = v ? 1 : 2;
      for (int j = 0; j < 4; j++) { float t = A[ra*4+j]; A[ra*4+j] = A[12+j]; A[12+j] = t; } }
    {
        float H[2][2] = {{cg[h2i], -sg[h2i]}, {sg[h2i], cg[h2i]}};
        float L[2][2] = {{cg[l2i], -sg[l2i]}, {sg[l2i], cg[l2i]}};
        for (int a = 0; a < 2; a++) for (int b = 0; b < 2; b++)
            for (int p = 0; p < 2; p++) for (int q = 0; q < 2; q++)
                B[(2*a+b)*4 + (2*p+q)] = H[a][p] * L[b][q];
    }
    for (int r = 0; r < 4; r++)
        for (int cl = 0; cl < 4; cl++) {
            float acc = 0.0f;
            for (int k = 0; k < 4; k++) acc += B[r*4+k] * A[k*4+cl];
            M[r*4+cl] = acc;
        }
    { const int rb = v ? 2 : 1;
      for (int j = 0; j < 4; j++) { float t = M[rb*4+j]; M[rb*4+j] = M[12+j]; M[12+j] = t; } }
    if (n == 13) {
        float ps, pc;
        sincosf(0.5f * qp[62], &ps, &pc);
        for (int j = 0; j < 4; j++) {
            float r0 = M[j],   r2 = M[8+j];
            M[j]   = pc * r0 - ps * r2;  M[8+j]  = ps * r0 + pc * r2;
            float r1 = M[4+j], r3 = M[12+j];
            M[4+j] = pc * r1 - ps * r3;  M[12+j] = ps * r1 + pc * r3;
        }
    }
    for (int i = 0; i < 16; i++) ws[16*n + i] = M[i];
}

__global__ __launch_bounds__(256) void qcnn_kernel(
    const float* __restrict__ x, const float* __restrict__ adj,
    const float* __restrict__ w_proj, const float* __restrict__ b_proj,
    const float* __restrict__ ws,
    const float* __restrict__ w1, const float* __restrict__ b1,
    const float* __restrict__ w2, const float* __restrict__ b2,
    const float* __restrict__ w3, const float* __restrict__ b3,
    float* __restrict__ out)
{
    const int lane = threadIdx.x & 63;
    const int wv   = threadIdx.x >> 6;
    const int gA   = blockIdx.x * 4 + wv;        // grid exact: 1656*4 == 6624
    const int gB   = gA + NPAIR;                 // same node, b += 32
    const int bA   = gA / NN;
    const int node = gA - bA * NN;

    const float* xpA = x + ((size_t)bA * SS * NN + node) * 2;
    const float* xpB = xpA + (size_t)32 * SS * NN * 2;

    Ct sA = init_state(xpA, w_proj, b_proj, lane);
    Ct sB = init_state(xpB, w_proj, b_proj, lane);

    // ---- adjacency permutation: shared mask (same node for both circuits) --
    const int cq = node & 7;
    int M = 0;
#pragma unroll
    for (int t = 0; t < 8; t++) {
        float avv = adj[cq * NN + t];
        if (t != cq && avv > 0.0f) M |= 1 << (7 - t);
    }
    if (M) {
        const int Mlane = M >> 2, Mlo = M & 3, pc = 7 - cq;
        Ct pA = adj_gather(sA, Mlane, Mlo);
        Ct pB = adj_gather(sB, Mlane, Mlo);
        adj_select(sA, pA, pc, lane);
        adj_select(sB, pB, pc, lane);
    }

    // ---- conv layers: fused 4x4 matrices + relayout (schedule R4-verified) --
    // Slot map: K1,K0 | L5..L0; init: 6,7 | 0,1,2,3,4,5
#define C2(OFF)  do { convm(sA, ws + (OFF)); convm(sB, ws + (OFF)); } while (0)
#define S12(J)   do { swkl1<J>(sA, lane); swkl1<J>(sB, lane); } while (0)
#define S02(J)   do { swkl0<J>(sA, lane); swkl0<J>(sB, lane); } while (0)
    C2(0);                       // (6,7)
    S12(1); S02(0);              // 4,5 | 0,1,2,3,6,7
    C2(16);                      // (4,5)
    S12(1);                      // 6,5 | 0,1,2,3,4,7
    C2(32);                      // (5,6)
    S12(3); S02(2);              // 2,3 | 0,1,6,5,4,7
    C2(48);                      // (2,3)
    S12(1);                      // 4,3 | 0,1,6,5,2,7
    C2(64);                      // (3,4)
    S12(5); S02(4);              // 0,1 | 4,3,6,5,2,7
    C2(80);                      // (0,1)
    S12(1);                      // 2,1 | 4,3,6,5,0,7
    C2(96);                      // (1,2)
    // layer 2
    S02(4);                      // 2,3 | 4,1,6,5,0,7
    C2(112);                     // (2,3)
    S12(1); S02(4);              // 0,1 | 4,3,6,5,2,7
    C2(128);                     // (0,1)
    S12(1);                      // 2,1 | 4,3,6,5,0,7
    C2(144);                     // (1,2)
    S12(5); S02(2);              // 4,5 | 2,3,6,1,0,7
    C2(160);                     // (4,5)
    S02(4);                      // 4,3 | 2,5,6,1,0,7
    C2(176);                     // (3,4)
    S12(3); S02(0);              // 6,7 | 2,5,4,1,0,3
    C2(192);                     // (6,7)
    S02(4);                      // 6,5 | 2,7,4,1,0,3
    C2(208);                     // (5,6) + pool RY(q6) folded
#undef C2
#undef S12
#undef S02
    // layout now: K1=q6, K0=q5 | L5=q2, L4=q7, L3=q4, L2=q1, L1=q0, L0=q3

    // ---- pool RY(q0), RY(q2), RY(q4): swap-in + in-lane rotation ----
    swkl0<1>(sA, lane); swkl0<1>(sB, lane);      // K0=q0, L1=q5
    ry_k0(sA, ws[224], ws[225]); ry_k0(sB, ws[224], ws[225]);   // RY(q0)
    swkl1<5>(sA, lane); swkl1<5>(sB, lane);      // K1=q2, L5=q6
    ry_k1(sA, ws[226], ws[227]); ry_k1(sB, ws[226], ws[227]);   // RY(q2)
    swkl0<3>(sA, lane); swkl0<3>(sB, lane);      // K0=q4, L3=q0
    ry_k0(sA, ws[228], ws[229]); ry_k0(sB, ws[228], ws[229]);   // RY(q4)
    // final layout: K1=q2, K0=q4 | L5=q6, L4=q7, L3=q0, L2=q1, L1=q5, L0=q3

    // ---- z reduction: WHT + readlane broadcast ----
    float WA, WB; v2f dkA, dkB;
    build_z(sA, lane, WA, dkA);
    build_z(sB, lane, WB, dkB);
    // qubit -> z: q0=W(8), q1=W(4), q2=dk.y, q3=W(1), q4=dk.x, q5=W(2),
    //             q6=W(32), q7=W(16)   (all wave-uniform)
    const float zA0 = rdl(WA, 8),  zA1 = rdl(WA, 4),  zA3 = rdl(WA, 1);
    const float zA5 = rdl(WA, 2),  zA6 = rdl(WA, 32), zA7 = rdl(WA, 16);
    const float zB0 = rdl(WB, 8),  zB1 = rdl(WB, 4),  zB3 = rdl(WB, 1);
    const float zB5 = rdl(WB, 2),  zB6 = rdl(WB, 32), zB7 = rdl(WB, 16);

    // ---- MLP head: 8 -> 64 (relu) -> 32 (relu) -> 1 ----
    const v4f* w1q = (const v4f*)(w1 + lane * 8);   // shared row for A and B
    const v4f wLo = w1q[0], wHi = w1q[1];
    float h1A = b1[lane];
    h1A = fmaf(zA0, wLo.x, h1A); h1A = fmaf(zA1, wLo.y, h1A);
    h1A = fmaf(dkA.y, wLo.z, h1A); h1A = fmaf(zA3, wLo.w, h1A);
    h1A = fmaf(dkA.x, wHi.x, h1A); h1A = fmaf(zA5, wHi.y, h1A);
    h1A = fmaf(zA6, wHi.z, h1A); h1A = fmaf(zA7, wHi.w, h1A);
    float h1B = b1[lane];
    h1B = fmaf(zB0, wLo.x, h1B); h1B = fmaf(zB1, wLo.y, h1B);
    h1B = fmaf(dkB.y, wLo.z, h1B); h1B = fmaf(zB3, wLo.w, h1B);
    h1B = fmaf(dkB.x, wHi.x, h1B); h1B = fmaf(zB5, wHi.y, h1B);
    h1B = fmaf(zB6, wHi.z, h1B); h1B = fmaf(zB7, wHi.w, h1B);
    h1A = fmaxf(h1A, 0.0f);
    h1B = fmaxf(h1B, 0.0f);

    // wave-local LDS staging (same wave writes then reads; broadcast reads)
    __shared__ float h1s[8][64];
    h1s[2 * wv][lane]     = h1A;
    h1s[2 * wv + 1][lane] = h1B;

    // half 0 computes circuit A's h2, half 1 circuit B's
    const int m = lane & 31;
    const v4f* hsv = (const v4f*)(&h1s[2 * wv + (lane >> 5)][0]);
    const v4f* w2v = (const v4f*)(w2 + m * 64);
    v4f acc4 = {0.0f, 0.0f, 0.0f, 0.0f};
#pragma unroll
    for (int j = 0; j < 16; j++)
        acc4 = __builtin_elementwise_fma(hsv[j], w2v[j], acc4);
    const float h2 = fmaxf(b2[m] + (acc4.x + acc4.y) + (acc4.z + acc4.w), 0.0f);

    float o = h2 * w3[m];
    o += sxc<1>(o); o += sxc<2>(o); o += sxc<4>(o); o += sxc<8>(o); o += sxc<16>(o);

    if (m == 0) out[(lane >> 5) ? gB : gA] = o + b3[0];
}

extern "C" void kernel_launch(void* const* d_in, const int* in_sizes, int n_in,
                              void* d_out, int out_size, void* d_ws, size_t ws_size,
                              hipStream_t stream) {
    const float* x      = (const float*)d_in[0];
    const float* adj    = (const float*)d_in[1];
    const float* w_proj = (const float*)d_in[2];
    const float* b_proj = (const float*)d_in[3];
    const float* qp     = (const float*)d_in[4];
    const float* w1     = (const float*)d_in[5];
    const float* b1     = (const float*)d_in[6];
    const float* w2     = (const float*)d_in[7];
    const float* b2     = (const float*)d_in[8];
    const float* w3     = (const float*)d_in[9];
    const float* b3     = (const float*)d_in[10];
    float* out = (float*)d_out;
    float* ws  = (float*)d_ws;                 // 230 floats

    hipLaunchKernelGGL(prep_kernel, dim3(1), dim3(64), 0, stream, qp, ws);
    hipLaunchKernelGGL(qcnn_kernel, dim3(NPAIR / 4), dim3(256), 0, stream,
                       x, adj, w_proj, b_proj, ws, w1, b1, w2, b2, w3, b3, out);
}